// Round 3
// baseline (214.698 us; speedup 1.0000x reference)
//
#include <hip/hip_runtime.h>
#include <hip/hip_fp16.h>
#include <stdint.h>
#include <math.h>

#define KB 512
#define KT 2048
#define KS 16
#define KPD 4

// ---------------- shared helpers ----------------
__device__ __forceinline__ float softplus_f(float x) {
    float ax = fabsf(x);
    float e  = __expf(-ax);
    return fmaxf(x, 0.0f) + __logf(1.0f + e);
}
__device__ __forceinline__ float sigmoid_f(float x) {
    return __builtin_amdgcn_rcpf(1.0f + __expf(-x));
}

__device__ __forceinline__ void mlp16(const float4 pv,
    const float* __restrict__ W1, const float* __restrict__ b1,
    const float* __restrict__ W2, const float* __restrict__ b2,
    float* __restrict__ acc)
{
#pragma unroll
    for (int j = 0; j < KS; ++j) acc[j] = b2[j];
#pragma unroll 4
    for (int k = 0; k < 64; ++k) {
        float hk = b1[k];
        hk = fmaf(pv.x, W1[k],       hk);
        hk = fmaf(pv.y, W1[64 + k],  hk);
        hk = fmaf(pv.z, W1[128 + k], hk);
        hk = fmaf(pv.w, W1[192 + k], hk);
        hk = fmaxf(hk, 0.0f);
#pragma unroll
        for (int j = 0; j < KS; ++j) acc[j] = fmaf(hk, W2[k * KS + j], acc[j]);
    }
}

// ---------------- K1: embarrassingly-parallel MLPs ----------------
// ws layout: qr_ws[b][s][t] (u32 = fp16 Q | fp16 R << 16), g_ws[b][t] (f32)
__global__ __launch_bounds__(256) void mlp_kernel(
    const float* __restrict__ p,
    const float* __restrict__ Wq1, const float* __restrict__ bq1,
    const float* __restrict__ Wq2, const float* __restrict__ bq2,
    const float* __restrict__ Wr1, const float* __restrict__ br1,
    const float* __restrict__ Wr2, const float* __restrict__ br2,
    const float* __restrict__ Wg1, const float* __restrict__ bg1,
    const float* __restrict__ Wg2, const float* __restrict__ bg2,
    uint32_t* __restrict__ qr_ws, float* __restrict__ g_ws)
{
    const int idx = blockIdx.x * 256 + threadIdx.x;   // global (b,t)
    const int b = idx >> 11;
    const int t = idx & (KT - 1);
    const float4 pv = reinterpret_cast<const float4*>(p)[idx];

    float accQ[KS], accR[KS];
    mlp16(pv, Wq1, bq1, Wq2, bq2, accQ);
    mlp16(pv, Wr1, br1, Wr2, br2, accR);

    float ag = bg2[0];
#pragma unroll 4
    for (int k = 0; k < 32; ++k) {
        float hk = bg1[k];
        hk = fmaf(pv.x, Wg1[k],      hk);
        hk = fmaf(pv.y, Wg1[32 + k], hk);
        hk = fmaf(pv.z, Wg1[64 + k], hk);
        hk = fmaf(pv.w, Wg1[96 + k], hk);
        hk = fmaxf(hk, 0.0f);
        ag = fmaf(hk, Wg2[k], ag);
    }
    g_ws[idx] = sigmoid_f(ag);

    uint32_t* qb = qr_ws + ((size_t)b << 15) + t;   // b*16*2048 + t
#pragma unroll
    for (int j = 0; j < KS; ++j) {
        float Qv = softplus_f(accQ[j]) + 1e-8f;
        float Rv = softplus_f(accR[j]) + 1e-8f;
        uint32_t lo = (uint32_t)__half_as_ushort(__float2half_rn(Qv));
        uint32_t hi = (uint32_t)__half_as_ushort(__float2half_rn(Rv));
        qb[(size_t)j * KT] = lo | (hi << 16);       // coalesced per j
    }
}

// ---------------- K2: register-streamed sequential scan ----------------
#define GS 32             // steps per group
#define NG (KT / GS)      // 64 groups

struct Grp {
    uint4  qr[8];         // 32 packed QR words
    float  z[GS];
    float4 g[8];          // 32 gammas
};

__device__ __forceinline__ void load_grp(Grp& G,
    const uint32_t* __restrict__ qrow, const float* __restrict__ zb,
    const float* __restrict__ gb, int s, int t0)
{
    const uint4* q4 = reinterpret_cast<const uint4*>(qrow + t0);
#pragma unroll
    for (int i = 0; i < 8; ++i) G.qr[i] = q4[i];
#pragma unroll
    for (int i = 0; i < GS; ++i) G.z[i] = zb[(size_t)(t0 + i) * KS + s];
    const float4* g4 = reinterpret_cast<const float4*>(gb + t0);
#pragma unroll
    for (int i = 0; i < 8; ++i) G.g[i] = g4[i];
}

__device__ __forceinline__ float h2f_lo(uint32_t w) {
    return __half2float(__ushort_as_half((unsigned short)(w & 0xffffu)));
}
__device__ __forceinline__ float h2f_hi(uint32_t w) {
    return __half2float(__ushort_as_half((unsigned short)(w >> 16)));
}

__device__ __forceinline__ void proc_grp(const Grp& G, float& mu, float& Pv,
                                         float* __restrict__ outp)
{
    const uint32_t* qw = reinterpret_cast<const uint32_t*>(&G.qr[0]);
    const float*    gf = reinterpret_cast<const float*>(&G.g[0]);
#pragma unroll
    for (int i = 0; i < GS; ++i) {
        float Q  = h2f_lo(qw[i]);
        float R  = h2f_hi(qw[i]);
        float Pp = Pv + Q;
        float Kk = Pp * __builtin_amdgcn_rcpf(Pp + R);
        Kk = fminf(fmaxf(Kk, 1e-6f), 0.95f);
        mu = fmaf(gf[i] * Kk, G.z[i] - mu, mu);
        Pv = fmaf(-Kk, Pp, Pp);
        outp[i * KS] = mu;
    }
}

__global__ __launch_bounds__(64, 1) void scan_kernel(
    const uint32_t* __restrict__ qr_ws, const float* __restrict__ g_ws,
    const float* __restrict__ z, const float* __restrict__ mu0,
    const float* __restrict__ P0, float* __restrict__ out)
{
    const int b = blockIdx.x;
    const int lane = threadIdx.x;
    if (lane >= KS) return;            // 16 active lanes, no barriers used
    const int s = lane;

    const uint32_t* qrow = qr_ws + ((size_t)b << 15) + (size_t)s * KT;
    const float* zb = z + (size_t)b * KT * KS;
    const float* gb = g_ws + (size_t)b * KT;
    float* ob = out + (size_t)b * KT * KS + s;

    float mu = mu0[b * KS + s];
    float Pv = P0[b * KS + s];

    Grp GA, GB;
    load_grp(GA, qrow, zb, gb, s, 0);
    for (int g2 = 0; g2 < NG / 2; ++g2) {
        const int t0 = g2 * (2 * GS);
        load_grp(GB, qrow, zb, gb, s, t0 + GS);
        proc_grp(GA, mu, Pv, ob + (size_t)t0 * KS);
        if (g2 + 1 < NG / 2) load_grp(GA, qrow, zb, gb, s, t0 + 2 * GS);
        proc_grp(GB, mu, Pv, ob + (size_t)(t0 + GS) * KS);
    }
}

// ---------------- fallback: R2 fused kernel (if ws too small) ----------------
#define KTT 128
#define KNT (KT / KTT)
#define SROW (KS + 1)

__global__ __launch_bounds__(320, 2) void kalman_fused(
    const float* __restrict__ z, const float* __restrict__ p,
    const float* __restrict__ mu0, const float* __restrict__ P0,
    const float* __restrict__ Wq1, const float* __restrict__ bq1,
    const float* __restrict__ Wq2, const float* __restrict__ bq2,
    const float* __restrict__ Wr1, const float* __restrict__ br1,
    const float* __restrict__ Wr2, const float* __restrict__ br2,
    const float* __restrict__ Wg1, const float* __restrict__ bg1,
    const float* __restrict__ Wg2, const float* __restrict__ bg2,
    float* __restrict__ out)
{
    __shared__ float sQ[2][KTT][SROW];
    __shared__ float sR[2][KTT][SROW];
    __shared__ float sZ[2][KTT][KS];
    __shared__ float sG[2][KTT];

    const int b = blockIdx.x;
    const int tid = threadIdx.x;
    const float* __restrict__ zb = z + (size_t)b * KT * KS;
    const float* __restrict__ pb = p + (size_t)b * KT * KPD;
    float* __restrict__ outb = out + (size_t)b * KT * KS;

    const bool is_mlp = (tid < 256);

    auto do_mlp_tile = [&](int tile, int buf) {
        const int tt = tid & (KTT - 1);
        const int t = tile * KTT + tt;
        const float4 pv = *reinterpret_cast<const float4*>(pb + (size_t)t * KPD);
        float acc[KS];
        if (tid < KTT) {
            mlp16(pv, Wq1, bq1, Wq2, bq2, acc);
#pragma unroll
            for (int j = 0; j < KS; ++j)
                sQ[buf][tt][j] = softplus_f(acc[j]) + 1e-8f;
            float ag = bg2[0];
#pragma unroll 8
            for (int k = 0; k < 32; ++k) {
                float hk = bg1[k];
                hk = fmaf(pv.x, Wg1[k],      hk);
                hk = fmaf(pv.y, Wg1[32 + k], hk);
                hk = fmaf(pv.z, Wg1[64 + k], hk);
                hk = fmaf(pv.w, Wg1[96 + k], hk);
                hk = fmaxf(hk, 0.0f);
                ag = fmaf(hk, Wg2[k], ag);
            }
            sG[buf][tt] = sigmoid_f(ag);
        } else {
            mlp16(pv, Wr1, br1, Wr2, br2, acc);
#pragma unroll
            for (int j = 0; j < KS; ++j)
                sR[buf][tt][j] = softplus_f(acc[j]) + 1e-8f;
        }
        const float4* __restrict__ zt =
            reinterpret_cast<const float4*>(zb + (size_t)tile * KTT * KS);
        float4* __restrict__ zd = reinterpret_cast<float4*>(&sZ[buf][0][0]);
        zd[tid] = zt[tid];
        zd[tid + 256] = zt[tid + 256];
    };

    float mu = 0.0f, Pv = 0.0f;
    if (!is_mlp) {
        const int lane = tid - 256;
        if (lane < KS) {
            mu = mu0[(size_t)b * KS + lane];
            Pv = P0[(size_t)b * KS + lane];
        }
    }

    if (is_mlp) do_mlp_tile(0, 0);
    __syncthreads();

    for (int k = 0; k < KNT; ++k) {
        const int cur = k & 1;
        if (is_mlp) {
            if (k + 1 < KNT) do_mlp_tile(k + 1, cur ^ 1);
        } else {
            const int lane = tid - 256;
            if (lane < KS) {
                const int s = lane;
                constexpr int U = 4;
                float Qc[U], Rc[U], Zc[U], Gc[U];
#pragma unroll
                for (int u = 0; u < U; ++u) {
                    Qc[u] = sQ[cur][u][s];
                    Rc[u] = sR[cur][u][s];
                    Zc[u] = sZ[cur][u][s];
                    Gc[u] = sG[cur][u];
                }
                for (int tt = 0; tt < KTT; tt += U) {
                    float Qn[U], Rn[U], Zn[U], Gn[U];
                    const bool more = (tt + U < KTT);
                    if (more) {
#pragma unroll
                        for (int u = 0; u < U; ++u) {
                            Qn[u] = sQ[cur][tt + U + u][s];
                            Rn[u] = sR[cur][tt + U + u][s];
                            Zn[u] = sZ[cur][tt + U + u][s];
                            Gn[u] = sG[cur][tt + U + u];
                        }
                    }
#pragma unroll
                    for (int u = 0; u < U; ++u) {
                        const float Ppred = Pv + Qc[u];
                        float Kk = Ppred * __builtin_amdgcn_rcpf(Ppred + Rc[u]);
                        Kk = fminf(fmaxf(Kk, 1e-6f), 0.95f);
                        mu = fmaf(Gc[u] * Kk, Zc[u] - mu, mu);
                        Pv = fmaf(-Kk, Ppred, Ppred);
                        outb[(size_t)(k * KTT + tt + u) * KS + s] = mu;
                    }
                    if (more) {
#pragma unroll
                        for (int u = 0; u < U; ++u) {
                            Qc[u] = Qn[u]; Rc[u] = Rn[u];
                            Zc[u] = Zn[u]; Gc[u] = Gn[u];
                        }
                    }
                }
            }
        }
        __syncthreads();
    }
}

// ---------------- launcher ----------------
extern "C" void kernel_launch(void* const* d_in, const int* in_sizes, int n_in,
                              void* d_out, int out_size, void* d_ws, size_t ws_size,
                              hipStream_t stream) {
    const float* z   = (const float*)d_in[0];
    const float* p   = (const float*)d_in[1];
    const float* mu0 = (const float*)d_in[2];
    const float* P0  = (const float*)d_in[3];
    const float* Wq1 = (const float*)d_in[4];
    const float* bq1 = (const float*)d_in[5];
    const float* Wq2 = (const float*)d_in[6];
    const float* bq2 = (const float*)d_in[7];
    const float* Wr1 = (const float*)d_in[8];
    const float* br1 = (const float*)d_in[9];
    const float* Wr2 = (const float*)d_in[10];
    const float* br2 = (const float*)d_in[11];
    const float* Wg1 = (const float*)d_in[12];
    const float* bg1 = (const float*)d_in[13];
    const float* Wg2 = (const float*)d_in[14];
    const float* bg2 = (const float*)d_in[15];
    float* out = (float*)d_out;

    const size_t QR_BYTES = (size_t)KB * KS * KT * 4;   // 67,108,864
    const size_t G_BYTES  = (size_t)KB * KT * 4;        //  4,194,304

    if (ws_size >= QR_BYTES + G_BYTES) {
        uint32_t* qr_ws = (uint32_t*)d_ws;
        float* g_ws = (float*)((char*)d_ws + QR_BYTES);
        hipLaunchKernelGGL(mlp_kernel, dim3((KB * KT) / 256), dim3(256), 0, stream,
                           p, Wq1, bq1, Wq2, bq2, Wr1, br1, Wr2, br2,
                           Wg1, bg1, Wg2, bg2, qr_ws, g_ws);
        hipLaunchKernelGGL(scan_kernel, dim3(KB), dim3(64), 0, stream,
                           qr_ws, g_ws, z, mu0, P0, out);
    } else {
        hipLaunchKernelGGL(kalman_fused, dim3(KB), dim3(320), 0, stream,
                           z, p, mu0, P0, Wq1, bq1, Wq2, bq2,
                           Wr1, br1, Wr2, br2, Wg1, bg1, Wg2, bg2, out);
    }
}